// Round 3
// baseline (35.206 us; speedup 1.0000x reference)
//
#include <hip/hip_runtime.h>

// Problem constants
#define NB   64    // B
#define DD   256   // D
#define TT   512   // T
#define KK   512   // K

typedef short bf8  __attribute__((ext_vector_type(8)));   // 8 x bf16 bits (4 VGPR)
typedef float f4   __attribute__((ext_vector_type(4)));
typedef float f16v __attribute__((ext_vector_type(16)));  // 32x32 MFMA acc

__device__ inline unsigned f2bf(float x) {
  unsigned u = __float_as_uint(x);
  u += 0x7FFFu + ((u >> 16) & 1u);   // round-to-nearest-even
  return u >> 16;
}

// D = A*B + D  (A rows = codewords k, B cols = t, reduction = d)
#define MFMA32(accv, va, vb) \
  asm("v_mfma_f32_32x32x16_bf16 %0, %1, %2, %0" : "+v"(accv) : "v"(va), "v"(vb))

#define ACC8(acc) \
  "+v"(acc[0][0]), "+v"(acc[0][1]), "+v"(acc[1][0]), "+v"(acc[1][1]), \
  "+v"(acc[2][0]), "+v"(acc[2][1]), "+v"(acc[3][0]), "+v"(acc[3][1])

// ---------------------------------------------------------------------------
// Kernel 1 (fused prep):
//   blocks 0..7  : M [D][K] fp32 -> MtF fragment-ordered bf16 + mnorm[k]
//                  MtF[(K32*16+ds)*64 + lane][j] = M[ds*16+(lane>>5)*8+j][K32*32+(lane&31)]
//   blocks 8..71 : rec partial sums (Xhat-X)^2 and Dhat partial sums
//   block 0 also zeroes the main-kernel completion counter.
// ---------------------------------------------------------------------------
__global__ __launch_bounds__(256) void edm_prep(
    const float* __restrict__ M, const float4* __restrict__ Xh,
    const float4* __restrict__ X, const float4* __restrict__ Dh,
    unsigned short* __restrict__ MtF, float* __restrict__ mnorm,
    float* __restrict__ recp, float* __restrict__ dhp,
    unsigned* __restrict__ counter) {
  __shared__ __align__(16) float tile[DD][68];
  __shared__ float pn[4][64];
  __shared__ float ps[8];

  const int bid  = blockIdx.x;
  const int tid  = threadIdx.x;
  const int lane = tid & 63;
  const int q    = tid >> 6;

  if (bid == 0 && tid == 0) *counter = 0u;

  if (bid < 8) {
    // ---- transpose block: k-range [bid*64, +64), all 256 d ----
    #pragma unroll
    for (int it = 0; it < 16; ++it) {
      const int d  = q * 64 + it * 4 + (lane >> 4);
      const int kc = (lane & 15) << 2;
      *(float4*)&tile[d][kc] = *(const float4*)(M + (size_t)d * KK + bid * 64 + kc);
    }
    __syncthreads();
    const int k   = bid * 64 + lane;
    const int K32 = k >> 5;
    const int c   = k & 31;
    float s = 0.f;
    #pragma unroll
    for (int dsl = 0; dsl < 4; ++dsl) {          // thread owns d in [q*64, +64)
      const int ds = q * 4 + dsl;
      #pragma unroll
      for (int h = 0; h < 2; ++h) {
        unsigned pk[4];
        #pragma unroll
        for (int e = 0; e < 4; ++e) {
          const float x0 = tile[ds * 16 + h * 8 + 2 * e + 0][lane];
          const float x1 = tile[ds * 16 + h * 8 + 2 * e + 1][lane];
          s += x0 * x0 + x1 * x1;
          pk[e] = f2bf(x0) | (f2bf(x1) << 16);
        }
        *(uint4*)(MtF + ((size_t)(K32 * 16 + ds) * 64 + c + 32 * h) * 8) =
            make_uint4(pk[0], pk[1], pk[2], pk[3]);
      }
    }
    pn[q][lane] = s;
    __syncthreads();
    if (q == 0) mnorm[k] = pn[0][lane] + pn[1][lane] + pn[2][lane] + pn[3][lane];
  } else {
    // ---- rec block ----
    const int r = bid - 8;
    float s = 0.f, sd = 0.f;
    #pragma unroll
    for (int i = 0; i < 4; ++i) {
      const int idx = r * 1024 + i * 256 + tid;
      const float4 a = Xh[idx];
      const float4 c = X[idx];
      const float e0 = a.x - c.x, e1 = a.y - c.y, e2 = a.z - c.z, e3 = a.w - c.w;
      s += e0 * e0 + e1 * e1 + e2 * e2 + e3 * e3;
    }
    if (tid < 128) {
      const float4 dd = Dh[r * 128 + tid];
      sd = dd.x + dd.y + dd.z + dd.w;
    }
    #pragma unroll
    for (int off = 32; off > 0; off >>= 1) {
      s  += __shfl_down(s, off);
      sd += __shfl_down(sd, off);
    }
    if (lane == 0) { ps[q] = s; ps[4 + q] = sd; }
    __syncthreads();
    if (tid == 0) {
      recp[r] = ps[0] + ps[1] + ps[2] + ps[3];
      dhp[r]  = ps[4] + ps[5] + ps[6] + ps[7];
    }
  }
}

// ---------------------------------------------------------------------------
// Kernel 2: main. 256 threads (4 waves), one block per (b, t-tile of 64).
// 512 blocks, ~51 KB LDS -> 2 blocks/CU (staging of one overlaps MFMA of other).
// Wave wv owns k in [wv*128, +128): acc[4 k-tiles][2 t-tiles] of 32x32.
// Last-finishing block does the final scalar combine (no 3rd kernel).
// ---------------------------------------------------------------------------
__global__ __launch_bounds__(256, 2) void edm_main(
    const float* __restrict__ H, const unsigned short* __restrict__ MtF,
    const float* __restrict__ mnorm, const float* __restrict__ recp,
    const float* __restrict__ dhp, float* __restrict__ d2part,
    unsigned* __restrict__ counter, float* __restrict__ out) {
  __shared__ __align__(16) float scratch[64][68];          // fp32 transpose staging
  __shared__ __align__(16) unsigned short Hbf[64 * 256];   // [t][d] bf16, XOR-swizzled
  __shared__ float hsum[64];
  __shared__ float wmin[4][64];
  __shared__ float red[12];
  __shared__ int   islast;

  const int tid = threadIdx.x;
  const int b   = blockIdx.x >> 3;
  const int t0  = (blockIdx.x & 7) << 6;
  const float* Hb = H + (size_t)b * DD * TT + t0;

  if (tid < 64) hsum[tid] = 0.f;

  const int tcol = tid & 63;
  const int q    = tid >> 6;
  float hacc = 0.f;

  for (int ch = 0; ch < 4; ++ch) {              // 4 chunks of 64 d-rows x 64 t
    #pragma unroll
    for (int ii = 0; ii < 4; ++ii) {            // coalesced global -> fp32 scratch
      const int f  = ii * 256 + tid;
      const int dl = f >> 4;
      const int t4 = (f & 15) << 2;
      *(float4*)&scratch[dl][t4] =
          *(const float4*)(Hb + (size_t)(ch * 64 + dl) * TT + t4);
    }
    __syncthreads();
    unsigned wpk[8];
    #pragma unroll
    for (int jj = 0; jj < 8; ++jj) {            // column read, convert, pack
      const float x0 = scratch[q * 16 + 2 * jj + 0][tcol];
      const float x1 = scratch[q * 16 + 2 * jj + 1][tcol];
      hacc += x0 * x0 + x1 * x1;
      wpk[jj] = f2bf(x0) | (f2bf(x1) << 16);
    }
    char* rowp = (char*)Hbf + tcol * 512;
    const int dbase2 = (ch * 64 + q * 16) * 2;
    const int swz = (tcol & 7) << 4;
    *(uint4*)(rowp + ((dbase2 +  0) ^ swz)) = make_uint4(wpk[0], wpk[1], wpk[2], wpk[3]);
    *(uint4*)(rowp + ((dbase2 + 16) ^ swz)) = make_uint4(wpk[4], wpk[5], wpk[6], wpk[7]);
    __syncthreads();
  }
  atomicAdd(&hsum[tcol], hacc);   // LDS atomic; consumed after post-wmin barrier

  // ---- MFMA phase (32x32x16) ----
  const int l  = tid & 63;
  const int wv = tid >> 6;
  const int kb = wv << 7;          // wave k-base (4 tiles of 32)
  const int h  = l >> 5;           // kk-half
  const int c  = l & 31;           // col within 32

  f16v acc[4][2];
  #pragma unroll
  for (int kt = 0; kt < 4; ++kt)
    #pragma unroll
    for (int tn = 0; tn < 2; ++tn)
      #pragma unroll
      for (int r = 0; r < 16; ++r) acc[kt][tn][r] = 0.f;
  asm volatile("s_nop 1" : ACC8(acc));          // VALU-write -> MFMA-read-C guard

  #pragma unroll 2
  for (int ds = 0; ds < 16; ++ds) {             // 16 x K=16 over d
    bf8 afr[4];
    #pragma unroll
    for (int kt = 0; kt < 4; ++kt)              // coalesced 1 KB fragment chunks
      afr[kt] = *(const bf8*)(MtF + ((size_t)((wv * 4 + kt) * 16 + ds) * 64 + l) * 8);
    #pragma unroll
    for (int tn = 0; tn < 2; ++tn) {
      const int t = tn * 32 + c;
      const bf8 bfr = *(const bf8*)((const char*)Hbf + t * 512 +
                                    ((ds * 32 + h * 16) ^ ((t & 7) << 4)));
      MFMA32(acc[0][tn], afr[0], bfr);
      MFMA32(acc[1][tn], afr[1], bfr);
      MFMA32(acc[2][tn], afr[2], bfr);
      MFMA32(acc[3][tn], afr[3], bfr);
    }
  }
  asm volatile("s_nop 7\n\ts_nop 7\n\ts_nop 7" : ACC8(acc));  // MFMA -> VALU guard

  // fold: k = kb + kt*32 + (r&3) + 8*(r>>2) + 4*h ; t = t0 + tn*32 + c
  float rmin[2] = {3.0e38f, 3.0e38f};
  #pragma unroll
  for (int kt = 0; kt < 4; ++kt) {
    #pragma unroll
    for (int seg = 0; seg < 4; ++seg) {
      const f4 mn = *(const f4*)(mnorm + kb + kt * 32 + seg * 8 + h * 4);
      #pragma unroll
      for (int rr = 0; rr < 4; ++rr) {
        const int r = seg * 4 + rr;
        rmin[0] = fminf(rmin[0], mn[rr] - 2.f * acc[kt][0][r]);
        rmin[1] = fminf(rmin[1], mn[rr] - 2.f * acc[kt][1][r]);
      }
    }
  }
  // combine the two kk-halves (same t, disjoint k rows)
  rmin[0] = fminf(rmin[0], __shfl_xor(rmin[0], 32));
  rmin[1] = fminf(rmin[1], __shfl_xor(rmin[1], 32));
  if (h == 0) { wmin[wv][c] = rmin[0]; wmin[wv][32 + c] = rmin[1]; }
  __syncthreads();

  if (tid < 64) {
    float v = fminf(fminf(wmin[0][tid], wmin[1][tid]),
                    fminf(wmin[2][tid], wmin[3][tid])) + hsum[tid];
    #pragma unroll
    for (int off = 32; off > 0; off >>= 1) v += __shfl_down(v, off);
    if (tid == 0)
      __hip_atomic_store(&d2part[blockIdx.x], v, __ATOMIC_RELEASE,
                         __HIP_MEMORY_SCOPE_AGENT);
  }

  // ---- last-block final combine ----
  if (tid == 0) {
    __threadfence();
    islast = (atomicAdd(counter, 1u) == 511u) ? 1 : 0;
  }
  __syncthreads();
  if (islast) {
    float a = __hip_atomic_load(&d2part[tid], __ATOMIC_RELAXED,
                                __HIP_MEMORY_SCOPE_AGENT)
            + __hip_atomic_load(&d2part[tid + 256], __ATOMIC_RELAXED,
                                __HIP_MEMORY_SCOPE_AGENT);
    float r  = (tid < 64) ? recp[tid] : 0.f;
    float dh = (tid < 64) ? dhp[tid]  : 0.f;
    #pragma unroll
    for (int off = 32; off > 0; off >>= 1) {
      a  += __shfl_down(a, off);
      r  += __shfl_down(r, off);
      dh += __shfl_down(dh, off);
    }
    const int w = tid >> 6;
    if ((tid & 63) == 0) { red[w] = a; red[4 + w] = r; red[8 + w] = dh; }
    __syncthreads();
    if (tid == 0) {
      const float d2sum  = red[0] + red[1] + red[2] + red[3];
      const float recsum = red[4] + red[5] + red[6] + red[7];
      const float dhsum  = red[8] + red[9] + red[10] + red[11];
      // loss = recsum/262144 + 0.25*2*d2sum/8388608 - 0.1*dhatsum/32768
      out[0] = recsum * (1.f / 262144.f)
             + d2sum  * (1.f / 16777216.f)
             - 0.1f * dhsum * (1.f / 32768.f);
    }
  }
}

extern "C" void kernel_launch(void* const* d_in, const int* in_sizes, int n_in,
                              void* d_out, int out_size, void* d_ws, size_t ws_size,
                              hipStream_t stream) {
  const float* Xh = (const float*)d_in[0];   // [64,8,512]
  const float* X  = (const float*)d_in[1];   // [64,8,512]
  const float* H  = (const float*)d_in[2];   // [64,256,512]
  const float* M  = (const float*)d_in[3];   // [256,512]
  const float* Dh = (const float*)d_in[4];   // [64,512]
  float* out = (float*)d_out;

  unsigned short* MtF = (unsigned short*)d_ws;                     // 256 KiB
  float* mnorm = (float*)((char*)d_ws + (size_t)KK * DD * 2);      // 512 f
  float* recp  = mnorm + KK;                                       // 64 f
  float* dhp   = recp + 64;                                        // 64 f
  float* d2p   = dhp + 64;                                         // 512 f
  unsigned* counter = (unsigned*)(d2p + 512);                      // 1 u32

  edm_prep<<<72, 256, 0, stream>>>(M, (const float4*)Xh, (const float4*)X,
                                   (const float4*)Dh, MtF, mnorm, recp, dhp,
                                   counter);
  edm_main<<<NB * (TT / 64), 256, 0, stream>>>(H, MtF, mnorm, recp, dhp,
                                               d2p, counter, out);
}

// Round 4
// 29.504 us; speedup vs baseline: 1.1933x; 1.1933x over previous
//
#include <hip/hip_runtime.h>

// Problem constants
#define NB   64    // B
#define DD   256   // D
#define TT   512   // T
#define KK   512   // K

typedef short bf8 __attribute__((ext_vector_type(8)));   // 8 x bf16 bits (4 VGPR)
typedef float f4  __attribute__((ext_vector_type(4)));

__device__ inline unsigned f2bf(float x) {
  unsigned u = __float_as_uint(x);
  u += 0x7FFFu + ((u >> 16) & 1u);   // round-to-nearest-even
  return u >> 16;
}

// D = A*B + D  (A rows = codewords k, B cols = t, reduction = d)
#define MFMA(accv, va, vb) \
  asm("v_mfma_f32_16x16x32_bf16 %0, %1, %2, %0" : "+v"(accv) : "v"(va), "v"(vb))

#define ACCROW(acc, kt) \
    "+v"(acc[kt][0]), "+v"(acc[kt][1]), "+v"(acc[kt][2]), "+v"(acc[kt][3]), \
    "+v"(acc[kt][4]), "+v"(acc[kt][5]), "+v"(acc[kt][6]), "+v"(acc[kt][7])
#define ACCLIST8(acc) ACCROW(acc,0), ACCROW(acc,1), ACCROW(acc,2), ACCROW(acc,3)

// asm global load (NOT tracked by compiler's waitcnt insertion — manual waits)
#define GLOAD16(dst, src) \
  asm volatile("global_load_dwordx4 %0, %1, off" : "=v"(dst) : "v"(src))

__device__ inline void gload_lds16(const void* g, void* l) {
  __builtin_amdgcn_global_load_lds(
      (const __attribute__((address_space(1))) unsigned*)g,
      (__attribute__((address_space(3))) unsigned*)l, 16, 0, 0);
}

// ---------------------------------------------------------------------------
// Kernel 1 (fused prep):
//   blocks 0..7  : M [D][K] fp32 -> MtF fragment-ordered bf16 + mnorm[k].
//     Fragment for (k-tile K16, ds) is 1 KB contiguous:
//     MtF[((K16*8+ds)*64 + l)*8 + j] = bf16(M[ds*32 + (l>>4)*8 + j][K16*16 + (l&15)])
//   blocks 8..71 : rec partial sums (Xhat-X)^2 and Dhat partial sums.
//   block 0 zeroes the completion counter.
// ---------------------------------------------------------------------------
__global__ __launch_bounds__(256) void edm_prep(
    const float* __restrict__ M, const float4* __restrict__ Xh,
    const float4* __restrict__ X, const float4* __restrict__ Dh,
    unsigned short* __restrict__ MtF, float* __restrict__ mnorm,
    float* __restrict__ recp, float* __restrict__ dhp,
    unsigned* __restrict__ counter) {
  __shared__ __align__(16) float tile[DD][68];
  __shared__ float pn[4][64];
  __shared__ float ps[8];

  const int bid  = blockIdx.x;
  const int tid  = threadIdx.x;
  const int lane = tid & 63;
  const int q    = tid >> 6;

  if (bid == 0 && tid == 0) *counter = 0u;

  if (bid < 8) {
    #pragma unroll
    for (int it = 0; it < 16; ++it) {
      const int d  = q * 64 + it * 4 + (lane >> 4);
      const int kc = (lane & 15) << 2;
      *(float4*)&tile[d][kc] = *(const float4*)(M + (size_t)d * KK + bid * 64 + kc);
    }
    __syncthreads();
    const int k    = bid * 64 + lane;
    const int k16  = k >> 4;
    const int r16k = k & 15;
    float s = 0.f;
    #pragma unroll
    for (int dsl = 0; dsl < 2; ++dsl) {          // thread owns d in [q*64, +64)
      const int ds = q * 2 + dsl;
      #pragma unroll
      for (int g = 0; g < 4; ++g) {
        unsigned pk[4];
        #pragma unroll
        for (int e = 0; e < 4; ++e) {
          const float x0 = tile[ds * 32 + g * 8 + 2 * e + 0][lane];
          const float x1 = tile[ds * 32 + g * 8 + 2 * e + 1][lane];
          s += x0 * x0 + x1 * x1;
          pk[e] = f2bf(x0) | (f2bf(x1) << 16);
        }
        *(uint4*)(MtF + ((size_t)(k16 * 8 + ds) * 64 + r16k + 16 * g) * 8) =
            make_uint4(pk[0], pk[1], pk[2], pk[3]);
      }
    }
    pn[q][lane] = s;
    __syncthreads();
    if (q == 0) mnorm[k] = pn[0][lane] + pn[1][lane] + pn[2][lane] + pn[3][lane];
  } else {
    const int r = bid - 8;
    float s = 0.f, sd = 0.f;
    #pragma unroll
    for (int i = 0; i < 4; ++i) {
      const int idx = r * 1024 + i * 256 + tid;
      const float4 a = Xh[idx];
      const float4 c = X[idx];
      const float e0 = a.x - c.x, e1 = a.y - c.y, e2 = a.z - c.z, e3 = a.w - c.w;
      s += e0 * e0 + e1 * e1 + e2 * e2 + e3 * e3;
    }
    if (tid < 128) {
      const float4 dd = Dh[r * 128 + tid];
      sd = dd.x + dd.y + dd.z + dd.w;
    }
    #pragma unroll
    for (int off = 32; off > 0; off >>= 1) {
      s  += __shfl_down(s, off);
      sd += __shfl_down(sd, off);
    }
    if (lane == 0) { ps[q] = s; ps[4 + q] = sd; }
    __syncthreads();
    if (tid == 0) {
      recp[r] = ps[0] + ps[1] + ps[2] + ps[3];
      dhp[r]  = ps[4] + ps[5] + ps[6] + ps[7];
    }
  }
}

// ---------------------------------------------------------------------------
// Kernel 2: main. 512 threads (8 waves), one block per (b, t-tile of 128).
// Software-pipelined d-chunks (4 x 64 d): global_load_lds H into double-buffered
// fp32 scratch with COUNTED vmcnt (never 0 mid-loop) + raw barriers; A-frags
// via asm loads issued a phase early. Wave wv owns k in [wv*64, +64).
// Last-finishing block performs the final scalar combine.
// ---------------------------------------------------------------------------
__global__ __launch_bounds__(512, 2) void edm_main(
    const float* __restrict__ H, const unsigned short* __restrict__ MtF,
    const float* __restrict__ mnorm, const float* __restrict__ recp,
    const float* __restrict__ dhp, float* __restrict__ d2part,
    unsigned* __restrict__ counter, float* __restrict__ out) {
  __shared__ __align__(16) float scratch[2][64][128];      // linear (DMA dest)
  __shared__ __align__(16) unsigned short Hbf[128 * 256];  // [t][d] bf16, swizzled
  __shared__ float hsum[128];
  __shared__ float wmin[8][128];
  __shared__ float red[12];
  __shared__ float bsum[2];
  __shared__ int   islast;

  const int tid  = threadIdx.x;
  const int wv   = tid >> 6;       // wave 0..7
  const int l    = tid & 63;
  const int tcol = tid & 127;      // convert: owned t column
  const int q    = tid >> 7;       // convert: row group 0..3
  const int r16  = l & 15;
  const int g    = l >> 4;

  const int b  = blockIdx.x >> 2;
  const int t0 = (blockIdx.x & 3) << 7;
  const float* Hb = H + (size_t)b * DD * TT + t0;

  if (tid < 128) hsum[tid] = 0.f;

  f4 acc[4][8];
  #pragma unroll
  for (int kt = 0; kt < 4; ++kt)
    #pragma unroll
    for (int tn = 0; tn < 8; ++tn)
      acc[kt][tn] = (f4){0.f, 0.f, 0.f, 0.f};
  asm volatile("s_nop 1" : ACCLIST8(acc));   // VALU-write -> MFMA-read-C guard

  // DMA: wave wv stages its 4 segments of chunk ch into scratch[buf]
  #define ISSUE_DMA(buf, ch)                                                  \
    {                                                                         \
      _Pragma("unroll")                                                       \
      for (int ii = 0; ii < 4; ++ii) {                                        \
        const int f  = ii * 512 + wv * 64;          /* wave-uniform base */   \
        const int fl = f + l;                                                 \
        const int dl = fl >> 5;                                               \
        const int t4 = (fl & 31) << 2;                                        \
        gload_lds16(Hb + (size_t)((ch) * 64 + dl) * TT + t4,                  \
                    (char*)&scratch[buf][0][0] + (size_t)f * 16);             \
      }                                                                       \
    }

  ISSUE_DMA(0, 0);   // prologue
  float hacc = 0.f;

  #pragma unroll
  for (int ch = 0; ch < 4; ++ch) {
    // ---- A-fragment asm loads for this chunk (2 ds-steps x 4 k-tiles) ----
    bf8 afr[2][4];
    #pragma unroll
    for (int s = 0; s < 2; ++s)
      #pragma unroll
      for (int kt = 0; kt < 4; ++kt)
        GLOAD16(afr[s][kt],
                (const void*)((const char*)MtF +
                              (((size_t)(wv * 4 + kt) * 8 + ch * 2 + s) * 64 + l) * 16));
    __builtin_amdgcn_sched_barrier(0);
    if (ch < 3) ISSUE_DMA((ch + 1) & 1, ch + 1);   // prefetch next chunk
    __builtin_amdgcn_sched_barrier(0);
    // wait: this chunk's DMA (oldest 4) done; A-frags + next DMA may fly
    if (ch < 3) asm volatile("s_waitcnt vmcnt(12)" ::: "memory");
    else        asm volatile("s_waitcnt vmcnt(8)"  ::: "memory");
    __builtin_amdgcn_s_barrier();
    asm volatile("" ::: "memory");

    // ---- convert chunk: fp32 scratch -> bf16 Hbf (XOR-swizzled rows) ----
    {
      unsigned wpk[8];
      #pragma unroll
      for (int jj = 0; jj < 8; ++jj) {
        const float x0 = scratch[ch & 1][q * 16 + 2 * jj + 0][tcol];
        const float x1 = scratch[ch & 1][q * 16 + 2 * jj + 1][tcol];
        hacc += x0 * x0 + x1 * x1;
        wpk[jj] = f2bf(x0) | (f2bf(x1) << 16);
      }
      char* rowp = (char*)Hbf + tcol * 512;
      const int dbase2 = (ch * 64 + q * 16) * 2;
      const int swz = (tcol & 7) << 4;
      *(uint4*)(rowp + ((dbase2 +  0) ^ swz)) = make_uint4(wpk[0], wpk[1], wpk[2], wpk[3]);
      *(uint4*)(rowp + ((dbase2 + 16) ^ swz)) = make_uint4(wpk[4], wpk[5], wpk[6], wpk[7]);
    }
    asm volatile("s_waitcnt lgkmcnt(0)" ::: "memory");
    __builtin_amdgcn_s_barrier();
    asm volatile("" ::: "memory");
    // wait: A-frags (next-oldest) done; next chunk's DMA still in flight
    if (ch < 3) asm volatile("s_waitcnt vmcnt(4)" ::: "memory");
    else        asm volatile("s_waitcnt vmcnt(0)" ::: "memory");
    __builtin_amdgcn_sched_barrier(0);

    // ---- MFMA: 2 ds-steps (K=32 each) x 8 t-tiles x 4 k-tiles ----
    #pragma unroll
    for (int s = 0; s < 2; ++s) {
      const int ds = ch * 2 + s;
      #pragma unroll
      for (int tn = 0; tn < 8; ++tn) {
        const int t = tn * 16 + r16;
        const bf8 bfr = *(const bf8*)((const char*)Hbf + t * 512 +
                                      ((ds * 64 + g * 16) ^ ((t & 7) << 4)));
        MFMA(acc[0][tn], afr[s][0], bfr);
        MFMA(acc[1][tn], afr[s][1], bfr);
        MFMA(acc[2][tn], afr[s][2], bfr);
        MFMA(acc[3][tn], afr[s][3], bfr);
      }
    }
  }
  asm volatile("s_nop 7\n\ts_nop 7" : ACCLIST8(acc));  // MFMA-write -> VALU-read guard

  atomicAdd(&hsum[tcol], hacc);   // LDS atomic; consumed after post-wmin barrier

  // fold: k = wv*64 + kt*16 + 4*g + rr (C/D row map: col=lane&15, row=4*(l>>4)+reg)
  float rmin[8] = {3.0e38f, 3.0e38f, 3.0e38f, 3.0e38f,
                   3.0e38f, 3.0e38f, 3.0e38f, 3.0e38f};
  #pragma unroll
  for (int kt = 0; kt < 4; ++kt) {
    const f4 mn = *(const f4*)(mnorm + wv * 64 + kt * 16 + g * 4);
    #pragma unroll
    for (int tn = 0; tn < 8; ++tn) {
      #pragma unroll
      for (int rr = 0; rr < 4; ++rr)
        rmin[tn] = fminf(rmin[tn], mn[rr] - 2.f * acc[kt][tn][rr]);
    }
  }
  #pragma unroll
  for (int tn = 0; tn < 8; ++tn) {
    rmin[tn] = fminf(rmin[tn], __shfl_xor(rmin[tn], 16));
    rmin[tn] = fminf(rmin[tn], __shfl_xor(rmin[tn], 32));
  }
  if (g == 0) {
    #pragma unroll
    for (int tn = 0; tn < 8; ++tn) wmin[wv][tn * 16 + r16] = rmin[tn];
  }
  __syncthreads();

  if (tid < 128) {
    float m = wmin[0][tid];
    #pragma unroll
    for (int w = 1; w < 8; ++w) m = fminf(m, wmin[w][tid]);
    float v = m + hsum[tid];
    #pragma unroll
    for (int off = 32; off > 0; off >>= 1) v += __shfl_down(v, off);
    if ((tid & 63) == 0) bsum[tid >> 6] = v;
  }
  __syncthreads();
  if (tid == 0) {
    __hip_atomic_store(&d2part[blockIdx.x], bsum[0] + bsum[1],
                       __ATOMIC_RELEASE, __HIP_MEMORY_SCOPE_AGENT);
    islast = (__hip_atomic_fetch_add(counter, 1u, __ATOMIC_ACQ_REL,
                                     __HIP_MEMORY_SCOPE_AGENT) == 255u) ? 1 : 0;
  }
  __syncthreads();

  if (islast) {
    float a = 0.f, r = 0.f, dh = 0.f;
    if (tid < 256) {
      a = __hip_atomic_load(&d2part[tid], __ATOMIC_RELAXED,
                            __HIP_MEMORY_SCOPE_AGENT);
      if (tid < 64) { r = recp[tid]; dh = dhp[tid]; }
    }
    #pragma unroll
    for (int off = 32; off > 0; off >>= 1) {
      a  += __shfl_down(a, off);
      r  += __shfl_down(r, off);
      dh += __shfl_down(dh, off);
    }
    if (tid < 256 && (tid & 63) == 0) {
      const int w = tid >> 6;
      red[w] = a; red[4 + w] = r; red[8 + w] = dh;
    }
    __syncthreads();
    if (tid == 0) {
      const float d2sum  = red[0] + red[1] + red[2] + red[3];
      const float recsum = red[4] + red[5] + red[6] + red[7];
      const float dhsum  = red[8] + red[9] + red[10] + red[11];
      // loss = recsum/262144 + 0.25*2*d2sum/8388608 - 0.1*dhsum/32768
      out[0] = recsum * (1.f / 262144.f)
             + d2sum  * (1.f / 16777216.f)
             - 0.1f * dhsum * (1.f / 32768.f);
    }
  }
}

extern "C" void kernel_launch(void* const* d_in, const int* in_sizes, int n_in,
                              void* d_out, int out_size, void* d_ws, size_t ws_size,
                              hipStream_t stream) {
  const float* Xh = (const float*)d_in[0];   // [64,8,512]
  const float* X  = (const float*)d_in[1];   // [64,8,512]
  const float* H  = (const float*)d_in[2];   // [64,256,512]
  const float* M  = (const float*)d_in[3];   // [256,512]
  const float* Dh = (const float*)d_in[4];   // [64,512]
  float* out = (float*)d_out;

  unsigned short* MtF = (unsigned short*)d_ws;                     // 256 KiB
  float* mnorm = (float*)((char*)d_ws + (size_t)KK * DD * 2);      // 512 f
  float* recp  = mnorm + KK;                                       // 64 f
  float* dhp   = recp + 64;                                        // 64 f
  float* d2p   = dhp + 64;                                         // 256 f
  unsigned* counter = (unsigned*)(d2p + 256);                      // 1 u32

  edm_prep<<<72, 256, 0, stream>>>(M, (const float4*)Xh, (const float4*)X,
                                   (const float4*)Dh, MtF, mnorm, recp, dhp,
                                   counter);
  edm_main<<<NB * (TT / 128), 512, 0, stream>>>(H, MtF, mnorm, recp, dhp,
                                                d2p, counter, out);
}

// Round 6
// 29.155 us; speedup vs baseline: 1.2076x; 1.0120x over previous
//
#include <hip/hip_runtime.h>

// Problem constants
#define NB   64    // B
#define DD   256   // D
#define TT   512   // T
#define KK   512   // K

typedef short bf8 __attribute__((ext_vector_type(8)));   // 8 x bf16 bits (4 VGPR)
typedef float f4  __attribute__((ext_vector_type(4)));

__device__ inline unsigned f2bf(float x) {
  unsigned u = __float_as_uint(x);
  u += 0x7FFFu + ((u >> 16) & 1u);   // round-to-nearest-even
  return u >> 16;
}

// D = A*B + D  (A rows = codewords k, B cols = t, reduction = d)
#define MFMA(accv, va, vb) \
  asm("v_mfma_f32_16x16x32_bf16 %0, %1, %2, %0" : "+v"(accv) : "v"(va), "v"(vb))

#define ACCROW(acc, kt) \
    "+v"(acc[kt][0]), "+v"(acc[kt][1]), "+v"(acc[kt][2]), "+v"(acc[kt][3]), \
    "+v"(acc[kt][4]), "+v"(acc[kt][5]), "+v"(acc[kt][6]), "+v"(acc[kt][7])
#define ACCLIST8(acc) ACCROW(acc,0), ACCROW(acc,1), ACCROW(acc,2), ACCROW(acc,3)

__device__ inline void gload_lds16(const void* g, void* l) {
  __builtin_amdgcn_global_load_lds(
      (const __attribute__((address_space(1))) unsigned*)g,
      (__attribute__((address_space(3))) unsigned*)l, 16, 0, 0);
}

// ---------------------------------------------------------------------------
// Kernel 1 (prep):
//   blocks 0..7  : M [D][K] fp32 -> MtF fragment-ordered bf16 + mnorm[k].
//     MtF[((k16*8+ds)*64 + l)*8 + j] = bf16(M[ds*32+(l>>4)*8+j][k16*16+(l&15)])
//   blocks 8..71 : rec partial sums (Xhat-X)^2 and Dhat partial sums.
//   block 0 zeroes the completion counter (kernel boundary publishes all).
// ---------------------------------------------------------------------------
__global__ __launch_bounds__(256) void edm_prep(
    const float* __restrict__ M, const float4* __restrict__ Xh,
    const float4* __restrict__ X, const float4* __restrict__ Dh,
    unsigned short* __restrict__ MtF, float* __restrict__ mnorm,
    float* __restrict__ recp, float* __restrict__ dhp,
    unsigned* __restrict__ counter) {
  __shared__ __align__(16) float tile[DD][68];
  __shared__ float pn[4][64];
  __shared__ float ps[8];

  const int bid  = blockIdx.x;
  const int tid  = threadIdx.x;
  const int lane = tid & 63;
  const int q    = tid >> 6;

  if (bid == 0 && tid == 0) *counter = 0u;

  if (bid < 8) {
    #pragma unroll
    for (int it = 0; it < 16; ++it) {
      const int d  = q * 64 + it * 4 + (lane >> 4);
      const int kc = (lane & 15) << 2;
      *(float4*)&tile[d][kc] = *(const float4*)(M + (size_t)d * KK + bid * 64 + kc);
    }
    __syncthreads();
    const int k    = bid * 64 + lane;
    const int k16  = k >> 4;
    const int r16k = k & 15;
    float s = 0.f;
    #pragma unroll
    for (int dsl = 0; dsl < 2; ++dsl) {          // thread owns d in [q*64, +64)
      const int ds = q * 2 + dsl;
      #pragma unroll
      for (int g = 0; g < 4; ++g) {
        unsigned pk[4];
        #pragma unroll
        for (int e = 0; e < 4; ++e) {
          const float x0 = tile[ds * 32 + g * 8 + 2 * e + 0][lane];
          const float x1 = tile[ds * 32 + g * 8 + 2 * e + 1][lane];
          s += x0 * x0 + x1 * x1;
          pk[e] = f2bf(x0) | (f2bf(x1) << 16);
        }
        *(uint4*)(MtF + ((size_t)(k16 * 8 + ds) * 64 + r16k + 16 * g) * 8) =
            make_uint4(pk[0], pk[1], pk[2], pk[3]);
      }
    }
    pn[q][lane] = s;
    __syncthreads();
    if (q == 0) mnorm[k] = pn[0][lane] + pn[1][lane] + pn[2][lane] + pn[3][lane];
  } else {
    const int r = bid - 8;
    float s = 0.f, sd = 0.f;
    #pragma unroll
    for (int i = 0; i < 4; ++i) {
      const int idx = r * 1024 + i * 256 + tid;
      const float4 a = Xh[idx];
      const float4 c = X[idx];
      const float e0 = a.x - c.x, e1 = a.y - c.y, e2 = a.z - c.z, e3 = a.w - c.w;
      s += e0 * e0 + e1 * e1 + e2 * e2 + e3 * e3;
    }
    if (tid < 128) {
      const float4 dd = Dh[r * 128 + tid];
      sd = dd.x + dd.y + dd.z + dd.w;
    }
    #pragma unroll
    for (int off = 32; off > 0; off >>= 1) {
      s  += __shfl_down(s, off);
      sd += __shfl_down(sd, off);
    }
    if (lane == 0) { ps[q] = s; ps[4 + q] = sd; }
    __syncthreads();
    if (tid == 0) {
      recp[r] = ps[0] + ps[1] + ps[2] + ps[3];
      dhp[r]  = ps[4] + ps[5] + ps[6] + ps[7];
    }
  }
}

// ---------------------------------------------------------------------------
// Kernel 2: main. 512 threads (8 waves), one block per (b, t-tile of 128),
// grid 256 = 1 block/CU. Compiler-scheduled 2-phase pipeline over 4 d-chunks:
//   per chunk: {read scratch[cur]->regs; issue DMA(next chunk); pack->Hbf;
//               MFMA(prev chunk); __syncthreads (compiler vmcnt/lgkm drain)}
// DMA flight overlaps convert + previous chunk's MFMA. No manual waitcnts.
// Wave wv owns k in [wv*64, +64). Last-finishing block combines everything.
// ---------------------------------------------------------------------------
__global__ __launch_bounds__(512, 2) void edm_main(
    const float* __restrict__ H, const unsigned short* __restrict__ MtF,
    const float* __restrict__ mnorm, const float* __restrict__ recp,
    const float* __restrict__ dhp, float* __restrict__ d2part,
    unsigned* __restrict__ counter, float* __restrict__ out) {
  __shared__ __align__(16) float scratch[2][64][128];      // linear (DMA dest)
  __shared__ __align__(16) unsigned short Hbf[128 * 256];  // [t][d] bf16, swizzled
  __shared__ float hsumP[4][128];
  __shared__ float wmin[8][128];
  __shared__ float red[12];
  __shared__ float bsum[2];
  __shared__ int   islast;

  const int tid  = threadIdx.x;
  const int wv   = tid >> 6;       // wave 0..7
  const int l    = tid & 63;
  const int tcol = tid & 127;      // convert: owned t column
  const int q    = tid >> 7;       // convert: d row-group 0..3
  const int r16  = l & 15;
  const int g    = l >> 4;

  const int b  = blockIdx.x >> 2;
  const int t0 = (blockIdx.x & 3) << 7;
  const float* Hb = H + (size_t)b * DD * TT + t0;

  // DMA: wave wv stages its 4 segments of chunk ch into scratch[buf]
  #define ISSUE_DMA(buf, ch)                                                  \
    {                                                                         \
      _Pragma("unroll")                                                       \
      for (int ii = 0; ii < 4; ++ii) {                                        \
        const int f  = ii * 512 + wv * 64;          /* wave-uniform base */   \
        const int fl = f + l;                                                 \
        const int dl = fl >> 5;                                               \
        const int t4 = (fl & 31) << 2;                                        \
        gload_lds16(Hb + (size_t)((ch) * 64 + dl) * TT + t4,                  \
                    (char*)&scratch[buf][0][0] + (size_t)f * 16);             \
      }                                                                       \
    }

  f4 acc[4][8];
  #pragma unroll
  for (int kt = 0; kt < 4; ++kt)
    #pragma unroll
    for (int tn = 0; tn < 8; ++tn)
      acc[kt][tn] = (f4){0.f, 0.f, 0.f, 0.f};
  asm volatile("s_nop 1" : ACCLIST8(acc));   // VALU-write -> MFMA-read-C guard

  // MFMA over one 64-d chunk cc: A frags (1 KB coalesced L2 reads) x Hbf LDS
  #define MFMA_CHUNK(cc)                                                      \
    {                                                                         \
      bf8 afr[2][4];                                                          \
      _Pragma("unroll")                                                       \
      for (int s = 0; s < 2; ++s)                                             \
        _Pragma("unroll")                                                     \
        for (int kt = 0; kt < 4; ++kt)                                        \
          afr[s][kt] = *(const bf8*)(MtF +                                    \
              (((size_t)(wv * 4 + kt) * 8 + (cc) * 2 + s) * 64 + l) * 8);     \
      _Pragma("unroll")                                                       \
      for (int s = 0; s < 2; ++s) {                                           \
        const int ds = (cc) * 2 + s;                                          \
        _Pragma("unroll")                                                     \
        for (int tn = 0; tn < 8; ++tn) {                                      \
          const int t = tn * 16 + r16;                                        \
          const bf8 bfr = *(const bf8*)((const char*)Hbf + t * 512 +          \
                              ((ds * 64 + g * 16) ^ ((t & 7) << 4)));         \
          MFMA(acc[0][tn], afr[s][0], bfr);                                   \
          MFMA(acc[1][tn], afr[s][1], bfr);                                   \
          MFMA(acc[2][tn], afr[s][2], bfr);                                   \
          MFMA(acc[3][tn], afr[s][3], bfr);                                   \
        }                                                                     \
      }                                                                       \
    }

  ISSUE_DMA(0, 0);
  __syncthreads();                 // chunk 0 resident (compiler vmcnt(0))

  float hacc = 0.f;
  #pragma unroll
  for (int ch = 0; ch < 4; ++ch) {
    // (a) read this chunk's column slice into regs (frees scratch aliasing)
    float xr[16];
    #pragma unroll
    for (int jj = 0; jj < 16; ++jj)
      xr[jj] = scratch[ch & 1][q * 16 + jj][tcol];
    // (b) issue next chunk's DMA (flies under pack + MFMA below)
    if (ch < 3) ISSUE_DMA((ch + 1) & 1, ch + 1);
    // (c) convert/pack -> Hbf chunk-ch region (XOR-swizzled rows)
    {
      unsigned wpk[8];
      #pragma unroll
      for (int jj = 0; jj < 8; ++jj) {
        const float x0 = xr[2 * jj + 0];
        const float x1 = xr[2 * jj + 1];
        hacc += x0 * x0 + x1 * x1;
        wpk[jj] = f2bf(x0) | (f2bf(x1) << 16);
      }
      char* rowp = (char*)Hbf + tcol * 512;
      const int dbase2 = (ch * 64 + q * 16) * 2;
      const int swz = (tcol & 7) << 4;
      *(uint4*)(rowp + ((dbase2 +  0) ^ swz)) = make_uint4(wpk[0], wpk[1], wpk[2], wpk[3]);
      *(uint4*)(rowp + ((dbase2 + 16) ^ swz)) = make_uint4(wpk[4], wpk[5], wpk[6], wpk[7]);
    }
    // (d) MFMA on the PREVIOUS chunk (its Hbf region is barrier-published)
    if (ch > 0) MFMA_CHUNK(ch - 1);
    __syncthreads();   // publish Hbf[ch]; compiler drains DMA(ch+1) here
  }
  MFMA_CHUNK(3);       // epilogue chunk
  asm volatile("s_nop 7\n\ts_nop 7" : ACCLIST8(acc));  // MFMA-write -> VALU guard

  hsumP[q][tcol] = hacc;           // unique slot per thread

  // fold: k = wv*64 + kt*16 + 4*g + rr (C/D map: col=lane&15, row=4*(l>>4)+reg)
  float rmin[8] = {3.0e38f, 3.0e38f, 3.0e38f, 3.0e38f,
                   3.0e38f, 3.0e38f, 3.0e38f, 3.0e38f};
  #pragma unroll
  for (int kt = 0; kt < 4; ++kt) {
    const f4 mn = *(const f4*)(mnorm + wv * 64 + kt * 16 + g * 4);
    #pragma unroll
    for (int tn = 0; tn < 8; ++tn) {
      #pragma unroll
      for (int rr = 0; rr < 4; ++rr)
        rmin[tn] = fminf(rmin[tn], mn[rr] - 2.f * acc[kt][tn][rr]);
    }
  }
  #pragma unroll
  for (int tn = 0; tn < 8; ++tn) {
    rmin[tn] = fminf(rmin[tn], __shfl_xor(rmin[tn], 16));
    rmin[tn] = fminf(rmin[tn], __shfl_xor(rmin[tn], 32));
  }
  if (g == 0) {
    #pragma unroll
    for (int tn = 0; tn < 8; ++tn) wmin[wv][tn * 16 + r16] = rmin[tn];
  }
  __syncthreads();

  if (tid < 128) {
    float m = wmin[0][tid];
    #pragma unroll
    for (int w = 1; w < 8; ++w) m = fminf(m, wmin[w][tid]);
    float v = m + hsumP[0][tid] + hsumP[1][tid] + hsumP[2][tid] + hsumP[3][tid];
    #pragma unroll
    for (int off = 32; off > 0; off >>= 1) v += __shfl_down(v, off);
    if ((tid & 63) == 0) bsum[tid >> 6] = v;
  }
  __syncthreads();
  if (tid == 0) {
    __hip_atomic_store(&d2part[blockIdx.x], bsum[0] + bsum[1],
                       __ATOMIC_RELEASE, __HIP_MEMORY_SCOPE_AGENT);
    islast = (__hip_atomic_fetch_add(counter, 1u, __ATOMIC_ACQ_REL,
                                     __HIP_MEMORY_SCOPE_AGENT) == 255u) ? 1 : 0;
  }
  __syncthreads();

  if (islast) {
    float a = 0.f, r = 0.f, dh = 0.f;
    if (tid < 256) {
      a = __hip_atomic_load(&d2part[tid], __ATOMIC_RELAXED,
                            __HIP_MEMORY_SCOPE_AGENT);
      if (tid < 64) { r = recp[tid]; dh = dhp[tid]; }
    }
    #pragma unroll
    for (int off = 32; off > 0; off >>= 1) {
      a  += __shfl_down(a, off);
      r  += __shfl_down(r, off);
      dh += __shfl_down(dh, off);
    }
    if (tid < 256 && (tid & 63) == 0) {
      const int w = tid >> 6;
      red[w] = a; red[4 + w] = r; red[8 + w] = dh;
    }
    __syncthreads();
    if (tid == 0) {
      const float d2sum  = red[0] + red[1] + red[2] + red[3];
      const float recsum = red[4] + red[5] + red[6] + red[7];
      const float dhsum  = red[8] + red[9] + red[10] + red[11];
      // loss = recsum/262144 + 0.25*2*d2sum/8388608 - 0.1*dhsum/32768
      out[0] = recsum * (1.f / 262144.f)
             + d2sum  * (1.f / 16777216.f)
             - 0.1f * dhsum * (1.f / 32768.f);
    }
  }
}

extern "C" void kernel_launch(void* const* d_in, const int* in_sizes, int n_in,
                              void* d_out, int out_size, void* d_ws, size_t ws_size,
                              hipStream_t stream) {
  const float* Xh = (const float*)d_in[0];   // [64,8,512]
  const float* X  = (const float*)d_in[1];   // [64,8,512]
  const float* H  = (const float*)d_in[2];   // [64,256,512]
  const float* M  = (const float*)d_in[3];   // [256,512]
  const float* Dh = (const float*)d_in[4];   // [64,512]
  float* out = (float*)d_out;

  unsigned short* MtF = (unsigned short*)d_ws;                     // 256 KiB
  float* mnorm = (float*)((char*)d_ws + (size_t)KK * DD * 2);      // 512 f
  float* recp  = mnorm + KK;                                       // 64 f
  float* dhp   = recp + 64;                                        // 64 f
  float* d2p   = dhp + 64;                                         // 256 f
  unsigned* counter = (unsigned*)(d2p + 256);                      // 1 u32

  edm_prep<<<72, 256, 0, stream>>>(M, (const float4*)Xh, (const float4*)X,
                                   (const float4*)Dh, MtF, mnorm, recp, dhp,
                                   counter);
  edm_main<<<NB * (TT / 128), 512, 0, stream>>>(H, MtF, mnorm, recp, dhp,
                                                d2p, counter, out);
}

// Round 7
// 28.698 us; speedup vs baseline: 1.2268x; 1.0159x over previous
//
#include <hip/hip_runtime.h>

// Problem constants
#define NB   64    // B
#define DD   256   // D
#define TT   512   // T
#define KK   512   // K

typedef short bf8 __attribute__((ext_vector_type(8)));   // 8 x bf16 bits (4 VGPR)
typedef float f4  __attribute__((ext_vector_type(4)));

__device__ inline unsigned f2bf(float x) {
  unsigned u = __float_as_uint(x);
  u += 0x7FFFu + ((u >> 16) & 1u);   // round-to-nearest-even
  return u >> 16;
}

// D = A*B + D  (A rows = codewords k, B cols = t, reduction = d)
#define MFMA(accv, va, vb) \
  asm("v_mfma_f32_16x16x32_bf16 %0, %1, %2, %0" : "+v"(accv) : "v"(va), "v"(vb))

#define ACCROW(acc, kt) \
    "+v"(acc[kt][0]), "+v"(acc[kt][1]), "+v"(acc[kt][2]), "+v"(acc[kt][3]), \
    "+v"(acc[kt][4]), "+v"(acc[kt][5]), "+v"(acc[kt][6]), "+v"(acc[kt][7])
#define ACCLIST8(acc) ACCROW(acc,0), ACCROW(acc,1), ACCROW(acc,2), ACCROW(acc,3)

// ---------------------------------------------------------------------------
// Kernel 1 (prep) — unchanged from R6 (verified):
//   blocks 0..7  : M [D][K] fp32 -> MtF fragment-ordered bf16 + mnorm[k].
//     MtF[((k16*8+ds)*64 + l)*8 + j] = bf16(M[ds*32+(l>>4)*8+j][k16*16+(l&15)])
//   blocks 8..71 : rec partial sums (Xhat-X)^2 and Dhat partial sums.
//   block 0 zeroes the completion counter (kernel boundary publishes all).
// ---------------------------------------------------------------------------
__global__ __launch_bounds__(256) void edm_prep(
    const float* __restrict__ M, const float4* __restrict__ Xh,
    const float4* __restrict__ X, const float4* __restrict__ Dh,
    unsigned short* __restrict__ MtF, float* __restrict__ mnorm,
    float* __restrict__ recp, float* __restrict__ dhp,
    unsigned* __restrict__ counter) {
  __shared__ __align__(16) float tile[DD][68];
  __shared__ float pn[4][64];
  __shared__ float ps[8];

  const int bid  = blockIdx.x;
  const int tid  = threadIdx.x;
  const int lane = tid & 63;
  const int q    = tid >> 6;

  if (bid == 0 && tid == 0) *counter = 0u;

  if (bid < 8) {
    #pragma unroll
    for (int it = 0; it < 16; ++it) {
      const int d  = q * 64 + it * 4 + (lane >> 4);
      const int kc = (lane & 15) << 2;
      *(float4*)&tile[d][kc] = *(const float4*)(M + (size_t)d * KK + bid * 64 + kc);
    }
    __syncthreads();
    const int k    = bid * 64 + lane;
    const int k16  = k >> 4;
    const int r16k = k & 15;
    float s = 0.f;
    #pragma unroll
    for (int dsl = 0; dsl < 2; ++dsl) {          // thread owns d in [q*64, +64)
      const int ds = q * 2 + dsl;
      #pragma unroll
      for (int g = 0; g < 4; ++g) {
        unsigned pk[4];
        #pragma unroll
        for (int e = 0; e < 4; ++e) {
          const float x0 = tile[ds * 32 + g * 8 + 2 * e + 0][lane];
          const float x1 = tile[ds * 32 + g * 8 + 2 * e + 1][lane];
          s += x0 * x0 + x1 * x1;
          pk[e] = f2bf(x0) | (f2bf(x1) << 16);
        }
        *(uint4*)(MtF + ((size_t)(k16 * 8 + ds) * 64 + r16k + 16 * g) * 8) =
            make_uint4(pk[0], pk[1], pk[2], pk[3]);
      }
    }
    pn[q][lane] = s;
    __syncthreads();
    if (q == 0) mnorm[k] = pn[0][lane] + pn[1][lane] + pn[2][lane] + pn[3][lane];
  } else {
    const int r = bid - 8;
    float s = 0.f, sd = 0.f;
    #pragma unroll
    for (int i = 0; i < 4; ++i) {
      const int idx = r * 1024 + i * 256 + tid;
      const float4 a = Xh[idx];
      const float4 c = X[idx];
      const float e0 = a.x - c.x, e1 = a.y - c.y, e2 = a.z - c.z, e3 = a.w - c.w;
      s += e0 * e0 + e1 * e1 + e2 * e2 + e3 * e3;
    }
    if (tid < 128) {
      const float4 dd = Dh[r * 128 + tid];
      sd = dd.x + dd.y + dd.z + dd.w;
    }
    #pragma unroll
    for (int off = 32; off > 0; off >>= 1) {
      s  += __shfl_down(s, off);
      sd += __shfl_down(sd, off);
    }
    if (lane == 0) { ps[q] = s; ps[4 + q] = sd; }
    __syncthreads();
    if (tid == 0) {
      recp[r] = ps[0] + ps[1] + ps[2] + ps[3];
      dhp[r]  = ps[4] + ps[5] + ps[6] + ps[7];
    }
  }
}

// ---------------------------------------------------------------------------
// Kernel 2: main. 512 threads (8 waves), one block per (b, t-tile of 128),
// grid 256. BARRIER-FREE staging: thread (q, tcol) gathers its own 64-d
// column slice of H with coalesced scalar loads (64 consecutive lanes =
// consecutive t), converts in registers, writes bf16 to Hbf via swizzled
// b128 stores. ONE __syncthreads, then the R2-style MFMA phase (compiler
// pipelines the register A-frag loads across ds — no barriers to defeat).
// Wave wv owns k in [wv*64, +64). Last-finishing block combines everything.
// ---------------------------------------------------------------------------
__global__ __launch_bounds__(512, 2) void edm_main(
    const float* __restrict__ H, const unsigned short* __restrict__ MtF,
    const float* __restrict__ mnorm, const float* __restrict__ recp,
    const float* __restrict__ dhp, float* __restrict__ d2part,
    unsigned* __restrict__ counter, float* __restrict__ out) {
  __shared__ __align__(16) unsigned short Hbf[128 * 256];  // [t][d] bf16, swizzled
  __shared__ float hsumP[4][128];
  __shared__ float wmin[8][128];
  __shared__ float red[12];
  __shared__ float bsum[2];
  __shared__ int   islast;

  const int tid  = threadIdx.x;
  const int wv   = tid >> 6;       // wave 0..7
  const int l    = tid & 63;
  const int tcol = tid & 127;      // owned t column
  const int q    = tid >> 7;       // d half-range group 0..3 (64 d each)
  const int r16  = l & 15;
  const int g    = l >> 4;

  const int b  = blockIdx.x >> 2;
  const int t0 = (blockIdx.x & 3) << 7;
  const float* Hcol = H + (size_t)b * DD * TT + t0 + tcol;  // column base

  // ---- staging: 4 rounds x 16 coalesced scalar loads -> pack -> Hbf ----
  float hacc = 0.f;
  char* rowp = (char*)Hbf + tcol * 512;
  const int swz = (tcol & 7) << 4;
  #pragma unroll
  for (int r = 0; r < 4; ++r) {
    float x[16];
    #pragma unroll
    for (int j = 0; j < 16; ++j)
      x[j] = Hcol[(size_t)(q * 64 + r * 16 + j) * TT];
    unsigned pk[8];
    #pragma unroll
    for (int e = 0; e < 8; ++e) {
      hacc += x[2 * e] * x[2 * e] + x[2 * e + 1] * x[2 * e + 1];
      pk[e] = f2bf(x[2 * e]) | (f2bf(x[2 * e + 1]) << 16);
    }
    const int dbyte = q * 128 + r * 32;        // byte offset of d-range in row
    *(uint4*)(rowp + ((dbyte +  0) ^ swz)) = make_uint4(pk[0], pk[1], pk[2], pk[3]);
    *(uint4*)(rowp + ((dbyte + 16) ^ swz)) = make_uint4(pk[4], pk[5], pk[6], pk[7]);
  }
  hsumP[q][tcol] = hacc;           // unique slot per thread

  f4 acc[4][8];
  #pragma unroll
  for (int kt = 0; kt < 4; ++kt)
    #pragma unroll
    for (int tn = 0; tn < 8; ++tn)
      acc[kt][tn] = (f4){0.f, 0.f, 0.f, 0.f};
  asm volatile("s_nop 1" : ACCLIST8(acc));   // VALU-write -> MFMA-read-C guard

  __syncthreads();                 // the ONLY staging barrier

  // ---- MFMA phase: 8 x K=32 over d; A frags 1 KB coalesced L2 reads ----
  #pragma unroll
  for (int ds = 0; ds < 8; ++ds) {
    bf8 afr[4];
    #pragma unroll
    for (int kt = 0; kt < 4; ++kt)
      afr[kt] = *(const bf8*)(MtF + (((size_t)(wv * 4 + kt) * 8 + ds) * 64 + l) * 8);
    #pragma unroll
    for (int tn = 0; tn < 8; ++tn) {
      const int t = tn * 16 + r16;
      const bf8 bfr = *(const bf8*)((const char*)Hbf + t * 512 +
                                    ((ds * 64 + g * 16) ^ ((t & 7) << 4)));
      MFMA(acc[0][tn], afr[0], bfr);
      MFMA(acc[1][tn], afr[1], bfr);
      MFMA(acc[2][tn], afr[2], bfr);
      MFMA(acc[3][tn], afr[3], bfr);
    }
  }
  asm volatile("s_nop 7\n\ts_nop 7" : ACCLIST8(acc));  // MFMA-write -> VALU guard

  // fold: k = wv*64 + kt*16 + 4*g + rr (C/D map: col=lane&15, row=4*(l>>4)+reg)
  float rmin[8] = {3.0e38f, 3.0e38f, 3.0e38f, 3.0e38f,
                   3.0e38f, 3.0e38f, 3.0e38f, 3.0e38f};
  #pragma unroll
  for (int kt = 0; kt < 4; ++kt) {
    const f4 mn = *(const f4*)(mnorm + wv * 64 + kt * 16 + g * 4);
    #pragma unroll
    for (int tn = 0; tn < 8; ++tn) {
      #pragma unroll
      for (int rr = 0; rr < 4; ++rr)
        rmin[tn] = fminf(rmin[tn], mn[rr] - 2.f * acc[kt][tn][rr]);
    }
  }
  #pragma unroll
  for (int tn = 0; tn < 8; ++tn) {
    rmin[tn] = fminf(rmin[tn], __shfl_xor(rmin[tn], 16));
    rmin[tn] = fminf(rmin[tn], __shfl_xor(rmin[tn], 32));
  }
  if (g == 0) {
    #pragma unroll
    for (int tn = 0; tn < 8; ++tn) wmin[wv][tn * 16 + r16] = rmin[tn];
  }
  __syncthreads();

  if (tid < 128) {
    float m = wmin[0][tid];
    #pragma unroll
    for (int w = 1; w < 8; ++w) m = fminf(m, wmin[w][tid]);
    float v = m + hsumP[0][tid] + hsumP[1][tid] + hsumP[2][tid] + hsumP[3][tid];
    #pragma unroll
    for (int off = 32; off > 0; off >>= 1) v += __shfl_down(v, off);
    if ((tid & 63) == 0) bsum[tid >> 6] = v;
  }
  __syncthreads();
  if (tid == 0) {
    __hip_atomic_store(&d2part[blockIdx.x], bsum[0] + bsum[1],
                       __ATOMIC_RELEASE, __HIP_MEMORY_SCOPE_AGENT);
    islast = (__hip_atomic_fetch_add(counter, 1u, __ATOMIC_ACQ_REL,
                                     __HIP_MEMORY_SCOPE_AGENT) == 255u) ? 1 : 0;
  }
  __syncthreads();

  if (islast) {
    float a = 0.f, r = 0.f, dh = 0.f;
    if (tid < 256) {
      a = __hip_atomic_load(&d2part[tid], __ATOMIC_RELAXED,
                            __HIP_MEMORY_SCOPE_AGENT);
      if (tid < 64) { r = recp[tid]; dh = dhp[tid]; }
    }
    #pragma unroll
    for (int off = 32; off > 0; off >>= 1) {
      a  += __shfl_down(a, off);
      r  += __shfl_down(r, off);
      dh += __shfl_down(dh, off);
    }
    if (tid < 256 && (tid & 63) == 0) {
      const int w = tid >> 6;
      red[w] = a; red[4 + w] = r; red[8 + w] = dh;
    }
    __syncthreads();
    if (tid == 0) {
      const float d2sum  = red[0] + red[1] + red[2] + red[3];
      const float recsum = red[4] + red[5] + red[6] + red[7];
      const float dhsum  = red[8] + red[9] + red[10] + red[11];
      // loss = recsum/262144 + 0.25*2*d2sum/8388608 - 0.1*dhsum/32768
      out[0] = recsum * (1.f / 262144.f)
             + d2sum  * (1.f / 16777216.f)
             - 0.1f * dhsum * (1.f / 32768.f);
    }
  }
}

extern "C" void kernel_launch(void* const* d_in, const int* in_sizes, int n_in,
                              void* d_out, int out_size, void* d_ws, size_t ws_size,
                              hipStream_t stream) {
  const float* Xh = (const float*)d_in[0];   // [64,8,512]
  const float* X  = (const float*)d_in[1];   // [64,8,512]
  const float* H  = (const float*)d_in[2];   // [64,256,512]
  const float* M  = (const float*)d_in[3];   // [256,512]
  const float* Dh = (const float*)d_in[4];   // [64,512]
  float* out = (float*)d_out;

  unsigned short* MtF = (unsigned short*)d_ws;                     // 256 KiB
  float* mnorm = (float*)((char*)d_ws + (size_t)KK * DD * 2);      // 512 f
  float* recp  = mnorm + KK;                                       // 64 f
  float* dhp   = recp + 64;                                        // 64 f
  float* d2p   = dhp + 64;                                         // 256 f
  unsigned* counter = (unsigned*)(d2p + 256);                      // 1 u32

  edm_prep<<<72, 256, 0, stream>>>(M, (const float4*)Xh, (const float4*)X,
                                   (const float4*)Dh, MtF, mnorm, recp, dhp,
                                   counter);
  edm_main<<<NB * (TT / 128), 512, 0, stream>>>(H, MtF, mnorm, recp, dhp,
                                                d2p, counter, out);
}